// Round 1
// baseline (882.289 us; speedup 1.0000x reference)
//
#include <hip/hip_runtime.h>
#include <hip/hip_bf16.h>
#include <stdint.h>

#define N_NODES 100000
#define N_EDGES 3200000
#define N_GRAPHS 64
#define NCHUNK 391  // ceil(N_NODES/256)

typedef unsigned int u32;
typedef unsigned short u16;
typedef __attribute__((ext_vector_type(8))) short bf16x8;
typedef __attribute__((ext_vector_type(4))) float f32x4;

__device__ __forceinline__ float bf_lo(u32 u){ return __uint_as_float(u << 16); }
__device__ __forceinline__ float bf_hi(u32 u){ return __uint_as_float(u & 0xffff0000u); }
__device__ __forceinline__ u16 f2bf(float f){
    union { __hip_bfloat16 h; u16 u; } c; c.h = __float2bfloat16(f); return c.u;
}

// ---- degree histogram (in-degree at dst) ----
__global__ void k_deg(const int* __restrict__ dst, int* __restrict__ deg){
    int e = blockIdx.x * blockDim.x + threadIdx.x;
    if (e < N_EDGES) atomicAdd(&deg[dst[e]], 1);
}

__global__ void k_dinv(const int* __restrict__ deg, float* __restrict__ dinv){
    int v = blockIdx.x * blockDim.x + threadIdx.x;
    if (v < N_NODES) dinv[v] = rsqrtf((float)deg[v] + 1.0f);  // +1 self loop
}

// ---- 3-pass exclusive scan of deg -> offsets (and cursor copy) ----
__global__ void k_scan1(const int* __restrict__ deg, int* __restrict__ bsum){
    __shared__ int sm[256];
    int idx = blockIdx.x * 256 + threadIdx.x;
    sm[threadIdx.x] = (idx < N_NODES) ? deg[idx] : 0;
    __syncthreads();
    for (int off = 128; off > 0; off >>= 1){
        if (threadIdx.x < off) sm[threadIdx.x] += sm[threadIdx.x + off];
        __syncthreads();
    }
    if (threadIdx.x == 0) bsum[blockIdx.x] = sm[0];
}

__global__ void k_scan2(const int* __restrict__ bsum, int* __restrict__ bpre){
    __shared__ int sm[512];
    int tid = threadIdx.x;
    int v = (tid < NCHUNK) ? bsum[tid] : 0;
    sm[tid] = v; __syncthreads();
    for (int off = 1; off < 512; off <<= 1){
        int t = (tid >= off) ? sm[tid - off] : 0;
        __syncthreads(); sm[tid] += t; __syncthreads();
    }
    if (tid < NCHUNK) bpre[tid] = sm[tid] - v;  // exclusive
}

__global__ void k_scan3(const int* __restrict__ deg, const int* __restrict__ bpre,
                        int* __restrict__ offsets, int* __restrict__ cursor){
    __shared__ int sm[256];
    int idx = blockIdx.x * 256 + threadIdx.x;
    int v = (idx < N_NODES) ? deg[idx] : 0;
    sm[threadIdx.x] = v; __syncthreads();
    for (int off = 1; off < 256; off <<= 1){
        int t = (threadIdx.x >= off) ? sm[threadIdx.x - off] : 0;
        __syncthreads(); sm[threadIdx.x] += t; __syncthreads();
    }
    int excl = sm[threadIdx.x] - v + bpre[blockIdx.x];
    if (idx < N_NODES){ offsets[idx] = excl; cursor[idx] = excl; }
    if (blockIdx.x == 0 && threadIdx.x == 0) offsets[N_NODES] = N_EDGES;
}

// ---- fill CSR buckets ----
__global__ void k_fill(const int* __restrict__ src, const int* __restrict__ dst,
                       const float* __restrict__ dinv, int* __restrict__ cursor,
                       int* __restrict__ csr_src, float* __restrict__ csr_norm){
    int e = blockIdx.x * blockDim.x + threadIdx.x;
    if (e >= N_EDGES) return;
    int s = src[e], d = dst[e];
    int pos = atomicAdd(&cursor[d], 1);
    csr_src[pos] = s;
    csr_norm[pos] = dinv[s] * dinv[d];
}

// ---- f32 -> packed bf16 pairs ----
__global__ void k_cvt_x(const float* __restrict__ x, u32* __restrict__ xb){
    int i = blockIdx.x * blockDim.x + threadIdx.x;  // one packed pair each
    if (i < N_NODES * 64){
        float2 f = reinterpret_cast<const float2*>(x)[i];
        xb[i] = (u32)f2bf(f.x) | ((u32)f2bf(f.y) << 16);
    }
}

// ---- W[K][N] f32 -> WT[N][K] bf16 (tiny) ----
__global__ void k_cvt_wt(const float* __restrict__ W, u16* __restrict__ WT, int K, int N){
    int i = blockIdx.x * blockDim.x + threadIdx.x;
    if (i < K * N){ int n = i / K, k = i % K; WT[i] = f2bf(W[k * N + n]); }
}

// ---- edge aggregation: out[v] = dinv[v]^2 * X[v] + sum_e norm_e * X[src_e]
// X is bf16 [N][128] as packed u32 pairs; one 64-lane group per node, 2 ch/lane.
template<bool OUT_BF16>
__global__ __launch_bounds__(256) void k_agg(const u32* __restrict__ X,
                      const int* __restrict__ offs, const int* __restrict__ csr_src,
                      const float* __restrict__ csr_norm, const float* __restrict__ dinv,
                      void* __restrict__ out){
    int lane = threadIdx.x & 63;
    int v = blockIdx.x * 4 + (threadIdx.x >> 6);
    float w = dinv[v]; w *= w;
    u32 u = X[v * 64 + lane];
    float a0 = w * bf_lo(u), a1 = w * bf_hi(u);
    int e1 = offs[v + 1];
    for (int e = offs[v]; e < e1; e += 64){
        int idx = e + lane; int sv = 0; float nv = 0.f;
        if (idx < e1){ sv = csr_src[idx]; nv = csr_norm[idx]; }
        int cnt = min(64, e1 - e);
        int j = 0;
        for (; j + 4 <= cnt; j += 4){
            int s0 = __shfl(sv, j), s1 = __shfl(sv, j+1), s2 = __shfl(sv, j+2), s3 = __shfl(sv, j+3);
            float w0 = __shfl(nv, j), w1 = __shfl(nv, j+1), w2 = __shfl(nv, j+2), w3 = __shfl(nv, j+3);
            u32 u0 = X[s0*64 + lane], u1 = X[s1*64 + lane], u2 = X[s2*64 + lane], u3 = X[s3*64 + lane];
            a0 += w0 * bf_lo(u0); a1 += w0 * bf_hi(u0);
            a0 += w1 * bf_lo(u1); a1 += w1 * bf_hi(u1);
            a0 += w2 * bf_lo(u2); a1 += w2 * bf_hi(u2);
            a0 += w3 * bf_lo(u3); a1 += w3 * bf_hi(u3);
        }
        for (; j < cnt; j++){
            int s = __shfl(sv, j); float ww = __shfl(nv, j);
            u32 uu = X[s*64 + lane];
            a0 += ww * bf_lo(uu); a1 += ww * bf_hi(uu);
        }
    }
    if (OUT_BF16){
        ((u32*)out)[v*64 + lane] = (u32)f2bf(a0) | ((u32)f2bf(a1) << 16);
    } else {
        ((float2*)out)[v*64 + lane] = make_float2(a0, a1);
    }
}

// ---- bf16 MFMA GEMM: C[M][BN] = A[M][BK] @ BT[BN][BK]^T (+bias)(+relu), bf16 out
// block: 256 thr (4 waves), BM=64 rows/block, each wave 16 rows x BN cols.
// LDS XOR-swizzle (byte ^= (row&7)<<4) kills the stride-256/512B bank conflict.
template<int BK, int BN, bool RELU, bool BIAS>
__global__ __launch_bounds__(256) void k_gemm(const u16* __restrict__ A, const u16* __restrict__ BT,
                        const float* __restrict__ bias, u16* __restrict__ C, int M){
    extern __shared__ char smem[];
    char* As = smem;                      // 64 x BK bf16, swizzled
    char* Bs = smem + 64 * BK * 2;        // BN x BK bf16, swizzled
    const int tid = threadIdx.x;
    const int rowbytes = BK * 2;
    {
        const int a16 = 64 * rowbytes / 16;
        for (int it = tid; it < a16; it += 256){
            int flat = it * 16;
            int r = flat / rowbytes, cb = flat % rowbytes;
            int grow = blockIdx.x * 64 + r;
            int4 val = make_int4(0,0,0,0);
            if (grow < M) val = *reinterpret_cast<const int4*>(A + grow * BK + cb / 2);
            *reinterpret_cast<int4*>(As + r * rowbytes + (cb ^ ((r & 7) << 4))) = val;
        }
        const int b16 = BN * rowbytes / 16;
        for (int it = tid; it < b16; it += 256){
            int flat = it * 16;
            int r = flat / rowbytes, cb = flat % rowbytes;
            int4 val = *reinterpret_cast<const int4*>(BT + r * BK + cb / 2);
            *reinterpret_cast<int4*>(Bs + r * rowbytes + (cb ^ ((r & 7) << 4))) = val;
        }
    }
    __syncthreads();

    const int wid = tid >> 6, lane = tid & 63;
    const int r0 = wid * 16;
    constexpr int NF = BN / 16;
    f32x4 acc[NF];
#pragma unroll
    for (int i = 0; i < NF; i++) acc[i] = (f32x4){0.f,0.f,0.f,0.f};
    const int ar = r0 + (lane & 15);
    const int koff = (lane >> 4) * 8;   // element offset within k-slice
#pragma unroll
    for (int kb = 0; kb < BK / 32; kb++){
        int kbyte = (kb * 32 + koff) * 2;
        bf16x8 aF = *reinterpret_cast<const bf16x8*>(As + ar * rowbytes + (kbyte ^ ((ar & 7) << 4)));
#pragma unroll
        for (int nf = 0; nf < NF; nf++){
            int bn = nf * 16 + (lane & 15);
            bf16x8 bF = *reinterpret_cast<const bf16x8*>(Bs + bn * rowbytes + (kbyte ^ ((bn & 7) << 4)));
            acc[nf] = __builtin_amdgcn_mfma_f32_16x16x32_bf16(aF, bF, acc[nf], 0, 0, 0);
        }
    }
#pragma unroll
    for (int nf = 0; nf < NF; nf++){
        int col = nf * 16 + (lane & 15);
        float bv = BIAS ? bias[col] : 0.f;
#pragma unroll
        for (int j = 0; j < 4; j++){
            int grow = blockIdx.x * 64 + r0 + (lane >> 4) * 4 + j;
            if (grow < M){
                float val = acc[nf][j] + bv;
                if (RELU) val = fmaxf(val, 0.f);
                C[grow * BN + col] = f2bf(val);
            }
        }
    }
}

// ---- pool: batch is sorted; run-accumulate in regs, flush per graph-run ----
__global__ void k_pool(const float* __restrict__ agg2f, const int* __restrict__ batch,
                       float* __restrict__ psum, float* __restrict__ counts){
    const int NPB = 200;  // grid=500
    int n0 = blockIdx.x * NPB, n1 = min(n0 + NPB, N_NODES);
    int tid = threadIdx.x;  // 128 = channel
    float racc = 0.f; int gcur = batch[n0]; int runlen = 0;
    for (int n = n0; n < n1; n++){
        int g = batch[n];
        if (g != gcur){
            atomicAdd(&psum[gcur * 128 + tid], racc);
            if (tid == 0) atomicAdd(&counts[gcur], (float)runlen);
            racc = 0.f; runlen = 0; gcur = g;
        }
        racc += agg2f[n * 128 + tid];
        runlen++;
    }
    atomicAdd(&psum[gcur * 128 + tid], racc);
    if (tid == 0) atomicAdd(&counts[gcur], (float)runlen);
}

__global__ void k_final(const float* __restrict__ psum, const float* __restrict__ counts,
                        const float* __restrict__ b2, float* __restrict__ out){
    int g = blockIdx.x, c = threadIdx.x;
    out[g * 128 + c] = psum[g * 128 + c] / fmaxf(counts[g], 1.0f) + b2[c];
}

extern "C" void kernel_launch(void* const* d_in, const int* in_sizes, int n_in,
                              void* d_out, int out_size, void* d_ws, size_t ws_size,
                              hipStream_t stream){
    const float* x   = (const float*)d_in[0];
    const int*   ei  = (const int*)d_in[1];
    const int* batch = (const int*)d_in[2];
    const float* W1  = (const float*)d_in[3];
    const float* b1  = (const float*)d_in[4];
    const float* W2  = (const float*)d_in[5];
    const float* b2  = (const float*)d_in[6];
    float* out = (float*)d_out;
    const int* esrc = ei;
    const int* edst = ei + N_EDGES;

    char* w = (char*)d_ws;
    size_t off = 0;
    auto alloc = [&](size_t bytes) -> char* {
        char* p = w + off; off += (bytes + 255) & ~size_t(255); return p;
    };
    int*   deg      = (int*)  alloc((size_t)N_NODES * 4);
    float* dinv     = (float*)alloc((size_t)N_NODES * 4);
    int*   offsets  = (int*)  alloc((size_t)(N_NODES + 1) * 4);
    int*   cursor   = (int*)  alloc((size_t)N_NODES * 4);
    int*   bsum     = (int*)  alloc((size_t)NCHUNK * 4);
    int*   bpre     = (int*)  alloc((size_t)NCHUNK * 4);
    int*   csr_src  = (int*)  alloc((size_t)N_EDGES * 4);
    float* csr_norm = (float*)alloc((size_t)N_EDGES * 4);
    u32*   xb       = (u32*)  alloc((size_t)N_NODES * 64 * 4);   // bf16 [N][128]
    u16*   aggx     = (u16*)  alloc((size_t)N_NODES * 128 * 2);  // bf16 [N][128]
    u16*   h        = (u16*)  alloc((size_t)N_NODES * 256 * 2);  // bf16 [N][256]
    u16*   t        = (u16*)  alloc((size_t)N_NODES * 128 * 2);  // bf16 [N][128]
    u16*   w1t      = (u16*)  alloc(128 * 256 * 2);
    u16*   w2t      = (u16*)  alloc(256 * 128 * 2);
    float* psum     = (float*)alloc((size_t)N_GRAPHS * 128 * 4);
    float* counts   = (float*)alloc((size_t)N_GRAPHS * 4);
    float* agg2f    = (float*)h;  // alias: h dead once t computed; agg2 f32 [N][128]

    hipMemsetAsync(deg, 0, (size_t)N_NODES * 4, stream);
    hipMemsetAsync(psum, 0, (size_t)N_GRAPHS * 128 * 4, stream);
    hipMemsetAsync(counts, 0, (size_t)N_GRAPHS * 4, stream);

    k_deg  <<<12500, 256, 0, stream>>>(edst, deg);
    k_dinv <<<391, 256, 0, stream>>>(deg, dinv);
    k_scan1<<<NCHUNK, 256, 0, stream>>>(deg, bsum);
    k_scan2<<<1, 512, 0, stream>>>(bsum, bpre);
    k_scan3<<<NCHUNK, 256, 0, stream>>>(deg, bpre, offsets, cursor);
    k_fill <<<12500, 256, 0, stream>>>(esrc, edst, dinv, cursor, csr_src, csr_norm);
    k_cvt_x<<<25000, 256, 0, stream>>>(x, xb);
    k_cvt_wt<<<128, 256, 0, stream>>>(W1, w1t, 128, 256);
    k_cvt_wt<<<128, 256, 0, stream>>>(W2, w2t, 256, 128);

    // layer 1: aggx = A_hat @ x  (bf16 out), h = relu(aggx @ W1 + b1)
    k_agg<true><<<25000, 256, 0, stream>>>(xb, offsets, csr_src, csr_norm, dinv, aggx);

    hipFuncSetAttribute(reinterpret_cast<const void*>(&k_gemm<128, 256, true, true>),
                        hipFuncAttributeMaxDynamicSharedMemorySize, 64*128*2 + 256*128*2);
    hipFuncSetAttribute(reinterpret_cast<const void*>(&k_gemm<256, 128, false, false>),
                        hipFuncAttributeMaxDynamicSharedMemorySize, 64*256*2 + 128*256*2);

    k_gemm<128, 256, true, true><<<1563, 256, 64*128*2 + 256*128*2, stream>>>(aggx, w1t, b1, h, N_NODES);
    // layer 2: t = h @ W2 (bf16), agg2f = A_hat @ t (f32), pooled mean + b2
    k_gemm<256, 128, false, false><<<1563, 256, 64*256*2 + 128*256*2, stream>>>(h, w2t, nullptr, t, N_NODES);
    k_agg<false><<<25000, 256, 0, stream>>>((const u32*)t, offsets, csr_src, csr_norm, dinv, (void*)agg2f);
    k_pool <<<500, 128, 0, stream>>>(agg2f, batch, psum, counts);
    k_final<<<N_GRAPHS, 128, 0, stream>>>(psum, counts, b2, out);
}